// Round 4
// baseline (531.215 us; speedup 1.0000x reference)
//
#include <hip/hip_runtime.h>
#include <hip/hip_bf16.h>

#define IN_F 4096
#define OUT_F 4096
#define M_ROWS 8192          // 4 * 2048
#define GROUP 128

// 32x32-shape tiled layout: granule = 512 shorts covering 32 rows x 16 k.
//   granule index g = (row>>5)*KT16 + (k>>4),  KT16 = IN_F/16 = 256
//   inner offset   = (((k>>3)&1)*32 + (row&31))*8 + (k&7)
// => global_load_lds (lds = base + lane*16) stages one granule per instr;
//    lane l lands holding frag[row=l&31][k=(l>>5)*8+j] — the MFMA
//    32x32x16_bf16 A/B fragment order (analog of the verified 16x16 granule).
#define KT16 (IN_F / 16)

typedef __attribute__((ext_vector_type(8))) short short8;
typedef __attribute__((ext_vector_type(16))) float floatx16;

__device__ __forceinline__ unsigned short f2bf(float f) {
    unsigned int u = __builtin_bit_cast(unsigned int, f);
    u += 0x7fffu + ((u >> 16) & 1u);   // RNE
    return (unsigned short)(u >> 16);
}

__device__ __forceinline__ void load_lds16(const unsigned short* g, unsigned short* l) {
    __builtin_amdgcn_global_load_lds(
        (const __attribute__((address_space(1))) void*)g,
        (__attribute__((address_space(3))) void*)l,
        16, 0, 0);
}

// ---------------------------------------------------------------------------
// Kernel 1: x fp32 -> xb bf16, 32x16 granule order. Block: 32 rows x 128 k.
// Grid: (IN_F/128, M_ROWS/32) = (32, 256). Coalesced reads (R3 fix kept):
// 8 consecutive lanes read 512 B contiguous.
// ---------------------------------------------------------------------------
__global__ __launch_bounds__(256) void convert_x_kernel(const float* __restrict__ x,
                                                        unsigned short* __restrict__ xb) {
    __shared__ unsigned short tile[32 * 128];   // 8 KB = 8 granules, output order

    const int t  = threadIdx.x;
    const int m0 = blockIdx.y * 32;
    const int k0 = blockIdx.x * 128;

    // phase 1: read 16 floats/thread, convert, write granule-order LDS
    {
        const int r = t >> 3;                  // row 0..31
        const int c = t & 7;                   // 16-float chunk 0..7 (one granule)
        const float4* src = (const float4*)(x + (size_t)(m0 + r) * IN_F + k0 + c * 16);
        float4 f[4];
#pragma unroll
        for (int i = 0; i < 4; ++i) f[i] = src[i];
        const float* fs = (const float*)f;
#pragma unroll
        for (int h = 0; h < 2; ++h) {          // two 8-element k-halves of granule c
            union { unsigned short us[8]; uint4 v; } o;
#pragma unroll
            for (int j = 0; j < 8; ++j) o.us[j] = f2bf(fs[h * 8 + j]);
            *(uint4*)&tile[c * 512 + (h * 32 + r) * 8] = o.v;
        }
    }

    __syncthreads();

    // phase 2: linear copy LDS -> global (block output = 8 granules contiguous)
    {
        unsigned short* dst = xb + ((size_t)blockIdx.y * KT16 + blockIdx.x * 8) * 512;
        *(uint4*)&dst[t * 8]        = *(const uint4*)&tile[t * 8];
        *(uint4*)&dst[2048 + t * 8] = *(const uint4*)&tile[2048 + t * 8];
    }
}

// ---------------------------------------------------------------------------
// Kernel 2: dequant -> wt bf16, 32x16 granule order ("rows" = output cols).
// Block: 64 n x 32 packed-k (=256 k). Grid: (512/32, 4096/64) = (16, 64).
// Same math as proven dequant (bit-identical values), new placement only.
// ---------------------------------------------------------------------------
__global__ __launch_bounds__(256) void dequant_kernel(const int* __restrict__ qw,
                                                      const int* __restrict__ qz,
                                                      const float* __restrict__ sc,
                                                      unsigned short* __restrict__ wt) {
    __shared__ unsigned short tile[2 * 16 * 512];   // 32 KB: [n-band][kt 0..15][512]

    const int t   = threadIdx.x;
    const int kp0 = blockIdx.x * 32;    // packed rows (8 k each)
    const int n0  = blockIdx.y * 64;

    {
        const int kp_l = t >> 3;            // 0..31
        const int nq   = t & 7;             // 8-n chunk
        const int kp   = kp0 + kp_l;
        const int g    = kp >> 4;
        const int nb   = n0 + nq * 8;

        const uint4 q0 = *(const uint4*)&qw[(size_t)kp * OUT_F + nb];
        const uint4 q1 = *(const uint4*)&qw[(size_t)kp * OUT_F + nb + 4];
        const unsigned zq = (unsigned)qz[g * (OUT_F / 8) + (nb >> 3)];
        const float4 s0 = *(const float4*)&sc[(size_t)g * OUT_F + nb];
        const float4 s1 = *(const float4*)&sc[(size_t)g * OUT_F + nb + 4];

        unsigned qv[8] = {q0.x, q0.y, q0.z, q0.w, q1.x, q1.y, q1.z, q1.w};
        float    sv[8] = {s0.x, s0.y, s0.z, s0.w, s1.x, s1.y, s1.z, s1.w};

        const int kt_l  = kp_l >> 1;        // granule-k 0..15
        const int khalf = kp_l & 1;         // k-half within granule
        const int nl    = nq >> 2;          // n-band 0/1

#pragma unroll
        for (int c = 0; c < 8; ++c) {
            const unsigned q = qv[c];
            const float zero = (float)(((zq >> (4 * c)) & 15u) + 1u);
            const float s = sv[c];
            const int nr = (nq & 3) * 8 + c;          // n within band, 0..31
            union { unsigned short us[8]; uint4 v; } o;
#pragma unroll
            for (int j = 0; j < 8; ++j) {
                const float w = (float)((q >> (4 * j)) & 15u);
                o.us[j] = f2bf(s * (w - zero));
            }
            *(uint4*)&tile[(nl * 16 + kt_l) * 512 + (khalf * 32 + nr) * 8] = o.v;
        }
    }

    __syncthreads();

    // phase 2: per n-band, 16 granules = 16 KB contiguous in global
    {
        const int nb0 = blockIdx.y * 2;     // global n-band base
        const int kt0 = blockIdx.x * 16;    // global granule-k base
#pragma unroll
        for (int band = 0; band < 2; ++band) {
            unsigned short* dst = wt + ((size_t)(nb0 + band) * KT16 + kt0) * 512;
            const unsigned short* srcl = &tile[band * 8192];
#pragma unroll
            for (int p = 0; p < 4; ++p)
                *(uint4*)&dst[p * 2048 + t * 8] = *(const uint4*)&srcl[p * 2048 + t * 8];
        }
    }
}

// ---------------------------------------------------------------------------
// Kernel 3: bf16 MFMA GEMM with 32x32x16 shape. 128x128 tile, BK=32,
// 4 waves (2x2), 256 thr — the proven R0 loop structure verbatim, only the
// MFMA shape/fragments changed (half the MFMA instruction count).
// Per wave: 2x2 tiles of 32x32, acc = 4 x floatx16 (64 VGPR).
// ---------------------------------------------------------------------------
__global__ __launch_bounds__(256) void gemm_kernel(const unsigned short* __restrict__ xb,
                                                   const unsigned short* __restrict__ wt,
                                                   const float* __restrict__ bias,
                                                   float* __restrict__ out) {
    __shared__ unsigned short As[8 * 512];   // 8 KB: [band 0..3][khalf 0..1]
    __shared__ unsigned short Bs[8 * 512];

    const int tid  = threadIdx.x;
    const int wid  = tid >> 6;          // 0..3
    const int lane = tid & 63;
    const int bx = blockIdx.x;          // n-block (128 cols)
    const int by = blockIdx.y;          // m-block (128 rows)
    const int wm = wid & 1;
    const int wn = wid >> 1;

    floatx16 acc[2][2] = {};

    // wave w stages A band by*4+w and B band bx*4+w (2 granules = 1 KB x2 per step,
    // consecutive in global since granules are k-consecutive within a band)
    const unsigned short* gA = xb + ((size_t)(by * 4 + wid) * KT16) * 512 + lane * 8;
    const unsigned short* gB = wt + ((size_t)(bx * 4 + wid) * KT16) * 512 + lane * 8;
    unsigned short* lA = &As[wid * 1024];
    unsigned short* lB = &Bs[wid * 1024];

    const unsigned short* aB = &As[wm * 2048 + lane * 8];   // bands wm*2, wm*2+1
    const unsigned short* bB = &Bs[wn * 2048 + lane * 8];   // bands wn*2, wn*2+1

    for (int kt = 0; kt < 128; ++kt) {        // 128 K-steps of 32 k (2 granules)
        __syncthreads();
        load_lds16(gA + kt * 1024,       lA);
        load_lds16(gA + kt * 1024 + 512, lA + 512);
        load_lds16(gB + kt * 1024,       lB);
        load_lds16(gB + kt * 1024 + 512, lB + 512);
        __syncthreads();

        short8 a[2][2], b[2][2];
#pragma unroll
        for (int i = 0; i < 2; ++i)
#pragma unroll
            for (int h = 0; h < 2; ++h) {
                a[i][h] = *(const short8*)(aB + (i * 2 + h) * 512);
                b[i][h] = *(const short8*)(bB + (i * 2 + h) * 512);
            }
#pragma unroll
        for (int h = 0; h < 2; ++h)
#pragma unroll
            for (int i = 0; i < 2; ++i)
#pragma unroll
                for (int j = 0; j < 2; ++j)
                    acc[i][j] = __builtin_amdgcn_mfma_f32_32x32x16_bf16(a[i][h], b[j][h], acc[i][j], 0, 0, 0);
    }

    // epilogue: 32x32 C/D layout: col = lane&31, row = (reg&3)+8*(reg>>2)+4*(lane>>5)
    const int col  = lane & 31;
    const int rhi  = 4 * (lane >> 5);
#pragma unroll
    for (int j = 0; j < 2; ++j) {
        const int n = bx * 128 + wn * 64 + j * 32 + col;
        const float bv = bias[n];
#pragma unroll
        for (int i = 0; i < 2; ++i) {
            const int m0 = by * 128 + wm * 64 + i * 32 + rhi;
#pragma unroll
            for (int r = 0; r < 16; ++r) {
                const int row = (r & 3) + 8 * (r >> 2);
                out[(size_t)(m0 + row) * OUT_F + n] = acc[i][j][r] + bv;
            }
        }
    }
}

extern "C" void kernel_launch(void* const* d_in, const int* in_sizes, int n_in,
                              void* d_out, int out_size, void* d_ws, size_t ws_size,
                              hipStream_t stream) {
    const float* x    = (const float*)d_in[0];
    const int*   qw   = (const int*)d_in[1];
    const int*   qz   = (const int*)d_in[2];
    const float* sc   = (const float*)d_in[3];
    const float* bias = (const float*)d_in[4];
    float* out = (float*)d_out;

    unsigned short* xb = (unsigned short*)d_ws;                       // 64 MiB tiled
    unsigned short* wt = xb + (size_t)M_ROWS * IN_F;                  // +32 MiB tiled

    convert_x_kernel<<<dim3(IN_F / 128, M_ROWS / 32), 256, 0, stream>>>(x, xb);
    dequant_kernel<<<dim3(IN_F / 8 / 32, OUT_F / 64), 256, 0, stream>>>(qw, qz, sc, wt);
    gemm_kernel<<<dim3(OUT_F / 128, M_ROWS / 128), 256, 0, stream>>>(xb, wt, bias, out);
}

// Round 5
// 498.935 us; speedup vs baseline: 1.0647x; 1.0647x over previous
//
#include <hip/hip_runtime.h>
#include <hip/hip_bf16.h>

#define IN_F 4096
#define OUT_F 4096
#define M_ROWS 8192          // 4 * 2048
#define GROUP 128

#define BM 128
#define BN 128
#define KT_TILES (IN_F / 32)   // 128 k-granules (16 rows x 32 k) per row-band

// Tiled workspace layout ("fragment order"):
//   element [row][k] -> granule ((row>>4)*KT_TILES + (k>>5)) of 512 shorts;
//   inner offset = (((k>>3)&3)*16 + (row&15))*8 + (k&7)
// so that global_load_lds (lds = base + lane*16) with per-lane gptr
// = granule_base + lane*16 stages a 1024 B CONTIGUOUS granule that lands in
// LDS already in MFMA fragment order (lane l = A[row=l&15][k=(l>>4)*8+j]).

typedef __attribute__((ext_vector_type(8))) short short8;
typedef __attribute__((ext_vector_type(4))) float floatx4;

__device__ __forceinline__ unsigned short f2bf(float f) {
    unsigned int u = __builtin_bit_cast(unsigned int, f);
    u += 0x7fffu + ((u >> 16) & 1u);   // RNE
    return (unsigned short)(u >> 16);
}

__device__ __forceinline__ void load_lds16(const unsigned short* g, unsigned short* l) {
    __builtin_amdgcn_global_load_lds(
        (const __attribute__((address_space(1))) void*)g,
        (__attribute__((address_space(3))) void*)l,
        16, 0, 0);
}

// ---------------------------------------------------------------------------
// Kernel 1: x fp32 -> xb bf16 tiled. 1024 blocks x 8 tiles (grid-stride):
// block b handles row-band by = b>>1, k-tiles bx = (b&1)*8 .. +8.
// Per tile: coalesced read (R3 fix: 16-lane groups read 1 KB contiguous),
// f2bf, LDS in granule order, linear 8 KB copy-out. Tile bytes identical
// to previous rounds. WG count 8192 -> 1024 (dispatch-overhead probe).
// ---------------------------------------------------------------------------
__global__ __launch_bounds__(256) void convert_x_kernel(const float* __restrict__ x,
                                                        unsigned short* __restrict__ xb) {
    __shared__ unsigned short tile[16 * 256];   // 8 KB, output (tiled) order

    const int t  = threadIdx.x;
    const int by = blockIdx.x >> 1;             // row-band 0..511
    const int m0 = by * 16;
    const int r  = t >> 4;                      // row 0..15
    const int c  = t & 15;                      // 16-float chunk 0..15

#pragma unroll 1
    for (int it = 0; it < 8; ++it) {
        const int bx = (blockIdx.x & 1) * 8 + it;   // 256-k tile 0..15
        const int k0 = bx * 256;

        if (it) __syncthreads();                // phase-2 readers of prev tile done

        // phase 1: read, convert, LDS write in granule order
        {
            const float4* src = (const float4*)(x + (size_t)(m0 + r) * IN_F + k0 + c * 16);
            float4 f[4];
#pragma unroll
            for (int i = 0; i < 4; ++i) f[i] = src[i];
            const float* fs = (const float*)f;
#pragma unroll
            for (int h = 0; h < 2; ++h) {       // two 8-element k-groups
                const int kl = c * 16 + h * 8;
                const int kt_l = kl >> 5;
                const int q    = (kl >> 3) & 3;
                union { unsigned short us[8]; uint4 v; } o;
#pragma unroll
                for (int j = 0; j < 8; ++j) o.us[j] = f2bf(fs[h * 8 + j]);
                *(uint4*)&tile[kt_l * 512 + (q * 16 + r) * 8] = o.v;
            }
        }

        __syncthreads();

        // phase 2: linear copy LDS -> global (tile output = 8 KB contiguous)
        {
            unsigned short* dst = xb + ((size_t)by * KT_TILES + bx * 8) * 512;
            *(uint4*)&dst[t * 8]        = *(const uint4*)&tile[t * 8];
            *(uint4*)&dst[2048 + t * 8] = *(const uint4*)&tile[2048 + t * 8];
        }
    }
}

// ---------------------------------------------------------------------------
// Kernel 2: dequant -> wt bf16 tiled. Block: 64 n x 32 kp (=256 k).
// Grid: (512/32, 4096/64) = (16, 64).  (round-0 version, proven)
// ---------------------------------------------------------------------------
#define DQ_KP 32
#define DQ_N  64

__global__ __launch_bounds__(256) void dequant_kernel(const int* __restrict__ qw,
                                                      const int* __restrict__ qz,
                                                      const float* __restrict__ sc,
                                                      unsigned short* __restrict__ wt) {
    __shared__ unsigned short tile[4 * 8 * 512];   // 32 KB: [tn_l][kt_l][512] tiled order

    const int t   = threadIdx.x;
    const int kp0 = blockIdx.x * DQ_KP;
    const int n0  = blockIdx.y * DQ_N;

    {
        const int kp_l = t >> 3;            // 0..31
        const int nq   = t & 7;             // 8-n chunk
        const int kp   = kp0 + kp_l;
        const int g    = kp >> 4;
        const int nb   = n0 + nq * 8;

        const uint4 q0 = *(const uint4*)&qw[(size_t)kp * OUT_F + nb];
        const uint4 q1 = *(const uint4*)&qw[(size_t)kp * OUT_F + nb + 4];
        const unsigned zq = (unsigned)qz[g * (OUT_F / 8) + (nb >> 3)];
        const float4 s0 = *(const float4*)&sc[(size_t)g * OUT_F + nb];
        const float4 s1 = *(const float4*)&sc[(size_t)g * OUT_F + nb + 4];

        unsigned qv[8] = {q0.x, q0.y, q0.z, q0.w, q1.x, q1.y, q1.z, q1.w};
        float    sv[8] = {s0.x, s0.y, s0.z, s0.w, s1.x, s1.y, s1.z, s1.w};

        const int kt_l  = kp_l >> 2;        // 0..7
        const int q_out = kp_l & 3;
        const int tn_l  = nq >> 1;

#pragma unroll
        for (int c = 0; c < 8; ++c) {
            const unsigned q = qv[c];
            const float zero = (float)(((zq >> (4 * c)) & 15u) + 1u);
            const float s = sv[c];
            const int r = (nq * 8 + c) & 15;
            union { unsigned short us[8]; uint4 v; } o;
#pragma unroll
            for (int j = 0; j < 8; ++j) {
                const float w = (float)((q >> (4 * j)) & 15u);
                o.us[j] = f2bf(s * (w - zero));
            }
            *(uint4*)&tile[(tn_l * 8 + kt_l) * 512 + (q_out * 16 + r) * 8] = o.v;
        }
    }

    __syncthreads();

    {
        const int tn0 = blockIdx.y * 4;
        const int kt0 = blockIdx.x * 8;
#pragma unroll
        for (int tn_l = 0; tn_l < 4; ++tn_l) {
            unsigned short* dst = wt + ((size_t)(tn0 + tn_l) * KT_TILES + kt0) * 512;
            const unsigned short* srcl = &tile[tn_l * 4096];
            *(uint4*)&dst[t * 8]        = *(const uint4*)&srcl[t * 8];
            *(uint4*)&dst[2048 + t * 8] = *(const uint4*)&srcl[2048 + t * 8];
        }
    }
}

// ---------------------------------------------------------------------------
// Kernel 3: bf16 MFMA GEMM — R0's proven 128x128 / 4-wave (2x2) structure,
// BK widened 32 -> 64: each sync-pair stages 32 KB (2 granules per row-band)
// and runs 32 MFMA/wave. Halves barrier count (128 -> 64) at unchanged
// occupancy (32 KB LDS -> up to 5 blocks/CU). Same k-order per accumulator
// as R0 -> bit-identical results.
// ---------------------------------------------------------------------------
__global__ __launch_bounds__(256) void gemm_kernel(const unsigned short* __restrict__ xb,
                                                   const unsigned short* __restrict__ wt,
                                                   const float* __restrict__ bias,
                                                   float* __restrict__ out) {
    __shared__ unsigned short As[2 * 8 * 512];   // 16 KB: [h 0..1][mt 0..7][512]
    __shared__ unsigned short Bs[2 * 8 * 512];

    const int tid  = threadIdx.x;
    const int wid  = tid >> 6;
    const int lane = tid & 63;
    const int TM0 = blockIdx.y * 8;          // first m-granule-row (16 rows each)
    const int TN0 = blockIdx.x * 8;
    const int wave_m = wid & 1;
    const int wave_n = wid >> 1;

    floatx4 acc[4][4] = {};

    // per-lane staging pointers: contiguous 1024 B per granule
    const unsigned short* ga0 = xb + ((size_t)(TM0 + wid + 0) * KT_TILES) * 512 + lane * 8;
    const unsigned short* ga1 = xb + ((size_t)(TM0 + wid + 4) * KT_TILES) * 512 + lane * 8;
    const unsigned short* gb0 = wt + ((size_t)(TN0 + wid + 0) * KT_TILES) * 512 + lane * 8;
    const unsigned short* gb1 = wt + ((size_t)(TN0 + wid + 4) * KT_TILES) * 512 + lane * 8;
    unsigned short* la0 = &As[(wid + 0) * 512];
    unsigned short* la1 = &As[(wid + 4) * 512];
    unsigned short* lb0 = &Bs[(wid + 0) * 512];
    unsigned short* lb1 = &Bs[(wid + 4) * 512];

    const int a_base = wave_m * 4 * 512 + lane * 8;
    const int b_base = wave_n * 4 * 512 + lane * 8;

    for (int s = 0; s < KT_TILES / 2; ++s) {     // 64 sync-pairs, 64 k each
        __syncthreads();
        // h=0 granules (k = 64s .. +31)
        load_lds16(ga0 + (size_t)s * 1024,       la0);
        load_lds16(ga1 + (size_t)s * 1024,       la1);
        load_lds16(gb0 + (size_t)s * 1024,       lb0);
        load_lds16(gb1 + (size_t)s * 1024,       lb1);
        // h=1 granules (k = 64s+32 .. +63)
        load_lds16(ga0 + (size_t)s * 1024 + 512, la0 + 4096);
        load_lds16(ga1 + (size_t)s * 1024 + 512, la1 + 4096);
        load_lds16(gb0 + (size_t)s * 1024 + 512, lb0 + 4096);
        load_lds16(gb1 + (size_t)s * 1024 + 512, lb1 + 4096);
        __syncthreads();

#pragma unroll
        for (int h = 0; h < 2; ++h) {
            short8 a[4], b[4];
#pragma unroll
            for (int i = 0; i < 4; ++i)
                a[i] = *(const short8*)&As[h * 4096 + a_base + i * 512];
#pragma unroll
            for (int j = 0; j < 4; ++j)
                b[j] = *(const short8*)&Bs[h * 4096 + b_base + j * 512];
#pragma unroll
            for (int i = 0; i < 4; ++i)
#pragma unroll
                for (int j = 0; j < 4; ++j)
                    acc[i][j] = __builtin_amdgcn_mfma_f32_16x16x32_bf16(a[i], b[j], acc[i][j], 0, 0, 0);
        }
    }

    // epilogue: C/D layout col = lane&15, row = (lane>>4)*4 + reg
    const int mrow = TM0 * 16 + wave_m * 64 + (lane >> 4) * 4;
    const int ncol = TN0 * 16 + wave_n * 64 + (lane & 15);
#pragma unroll
    for (int j = 0; j < 4; ++j) {
        const int n = ncol + j * 16;
        const float bv = bias[n];
#pragma unroll
        for (int i = 0; i < 4; ++i) {
            const int m = mrow + i * 16;
#pragma unroll
            for (int r = 0; r < 4; ++r)
                out[(size_t)(m + r) * OUT_F + n] = acc[i][j][r] + bv;
        }
    }
}

extern "C" void kernel_launch(void* const* d_in, const int* in_sizes, int n_in,
                              void* d_out, int out_size, void* d_ws, size_t ws_size,
                              hipStream_t stream) {
    const float* x    = (const float*)d_in[0];
    const int*   qw   = (const int*)d_in[1];
    const int*   qz   = (const int*)d_in[2];
    const float* sc   = (const float*)d_in[3];
    const float* bias = (const float*)d_in[4];
    float* out = (float*)d_out;

    unsigned short* xb = (unsigned short*)d_ws;                       // 64 MiB tiled
    unsigned short* wt = xb + (size_t)M_ROWS * IN_F;                  // +32 MiB tiled

    convert_x_kernel<<<dim3(1024), 256, 0, stream>>>(x, xb);
    dequant_kernel<<<dim3(IN_F / 8 / DQ_KP, OUT_F / DQ_N), 256, 0, stream>>>(qw, qz, sc, wt);
    gemm_kernel<<<dim3(OUT_F / BN, M_ROWS / BM), 256, 0, stream>>>(xb, wt, bias, out);
}